// Round 8
// baseline (782.497 us; speedup 1.0000x reference)
//
#include <hip/hip_runtime.h>
#include <stdint.h>

// ---------------------------------------------------------------------------
// GCN 2-layer: out = Ahat( dropout(elu( Ahat(x@W1)+b1 )) @ W2 ) + b2
// Ahat = D^-1/2 (A+I) D^-1/2
// dropout = jax threefry2x32 key(42), p=0.25, partitionable path.
// R7->R8: GEMM gets __launch_bounds__(256,3) + true ping-pong dbuf (R7's
// VGPR_Count=60 proved the compiler serialized the prefetch); CSR build
// loses 2 launches (dinv folded into scan1, cursor written by scan3).
// ---------------------------------------------------------------------------

typedef __bf16 bf16x8 __attribute__((ext_vector_type(8)));
typedef float floatx4 __attribute__((ext_vector_type(4)));
typedef _Float16 f16;
typedef _Float16 f16x8 __attribute__((ext_vector_type(8)));

union BF8 {
  bf16x8 v;
  unsigned short u[8];
  uint4 q;
};

union F16x8 {
  f16x8 v;
  uint4 q;
};

// ---------------- Threefry-2x32, key = (0, 42), 20 rounds ------------------
__device__ __forceinline__ void tf_round(uint32_t& x0, uint32_t& x1, int r) {
  x0 += x1;
  x1 = (x1 << r) | (x1 >> (32 - r));
  x1 ^= x0;
}

__device__ __forceinline__ void threefry_0_42(uint32_t c0, uint32_t c1,
                                              uint32_t& o0, uint32_t& o1) {
  const uint32_t ks0 = 0u;
  const uint32_t ks1 = 42u;
  const uint32_t ks2 = 0x1BD11BDAu ^ 0u ^ 42u;
  uint32_t x0 = c0 + ks0;
  uint32_t x1 = c1 + ks1;
  tf_round(x0, x1, 13); tf_round(x0, x1, 15); tf_round(x0, x1, 26); tf_round(x0, x1, 6);
  x0 += ks1; x1 += ks2 + 1u;
  tf_round(x0, x1, 17); tf_round(x0, x1, 29); tf_round(x0, x1, 16); tf_round(x0, x1, 24);
  x0 += ks2; x1 += ks0 + 2u;
  tf_round(x0, x1, 13); tf_round(x0, x1, 15); tf_round(x0, x1, 26); tf_round(x0, x1, 6);
  x0 += ks0; x1 += ks1 + 3u;
  tf_round(x0, x1, 17); tf_round(x0, x1, 29); tf_round(x0, x1, 16); tf_round(x0, x1, 24);
  x0 += ks1; x1 += ks2 + 4u;
  tf_round(x0, x1, 13); tf_round(x0, x1, 15); tf_round(x0, x1, 26); tf_round(x0, x1, 6);
  x0 += ks2; x1 += ks0 + 5u;
  o0 = x0; o1 = x1;
}

// split fp32 -> bf16 hi (truncate) + bf16 lo (truncate of residual)
__device__ __forceinline__ void split_bf16(float x, unsigned short& hi, unsigned short& lo) {
  uint32_t b = __float_as_uint(x);
  hi = (unsigned short)(b >> 16);
  float hif = __uint_as_float(b & 0xffff0000u);
  float lof = x - hif;  // exact
  lo = (unsigned short)(__float_as_uint(lof) >> 16);
}

// ---------------- degree -----------------------------------------------
__global__ void k_deg(const int* __restrict__ dst, int E, int* __restrict__ deg) {
  int e = blockIdx.x * blockDim.x + threadIdx.x;
  if (e < E) atomicAdd(&deg[dst[e]], 1);
}

// ---------------- 3-phase exclusive scan (+ dinv fused) --------------------
__global__ __launch_bounds__(256) void k_scan1(const int* __restrict__ deg,
                                               int* __restrict__ excl,
                                               int* __restrict__ sums,
                                               float* __restrict__ dinv, int N) {
  __shared__ int sm[256];
  int tid = threadIdx.x;
  int i = blockIdx.x * 256 + tid;
  int v = (i < N) ? deg[i] : 0;
  if (i < N) dinv[i] = 1.0f / sqrtf((float)(v + 1));  // +1 self loop
  sm[tid] = v;
  __syncthreads();
#pragma unroll
  for (int off = 1; off < 256; off <<= 1) {
    int t = (tid >= off) ? sm[tid - off] : 0;
    __syncthreads();
    sm[tid] += t;
    __syncthreads();
  }
  if (i < N) excl[i] = sm[tid] - v;
  if (tid == 255) sums[blockIdx.x] = sm[255];
}

__global__ __launch_bounds__(1024) void k_scan2(int* __restrict__ sums, int nb) {
  __shared__ int sm[1024];
  int tid = threadIdx.x;
  int v = (tid < nb) ? sums[tid] : 0;
  sm[tid] = v;
  __syncthreads();
#pragma unroll
  for (int off = 1; off < 1024; off <<= 1) {
    int t = (tid >= off) ? sm[tid - off] : 0;
    __syncthreads();
    sm[tid] += t;
    __syncthreads();
  }
  if (tid < nb) sums[tid] = sm[tid] - v;  // exclusive, in place
}

__global__ void k_scan3(int* __restrict__ rowptr, int* __restrict__ cursor,
                        const int* __restrict__ sums, int N, int E) {
  int i = blockIdx.x * blockDim.x + threadIdx.x;
  if (i < N) {
    int r = rowptr[i] + sums[i >> 8];
    rowptr[i] = r;
    cursor[i] = r;
  }
  if (i == 0) rowptr[N] = E;
}

// ---------------- bucket edges by dst --------------------------------------
__global__ void k_bucket(const int* __restrict__ src, const int* __restrict__ dst,
                         int* __restrict__ cursor, int* __restrict__ csr_src, int E) {
  int e = blockIdx.x * blockDim.x + threadIdx.x;
  if (e < E) {
    int pos = atomicAdd(&cursor[dst[e]], 1);
    csr_src[pos] = src[e];
  }
}

// -------- prep: W1 [512][256] fp32 -> packed fragment-major bf16 hi/lo -----
// uint4 entry index = ((ks*16 + nt)*2 + plane)*64 + lane;
// lane = quad*16 + (n&15), k = ks*32 + quad*8 + j, nt = n>>4.
__global__ void k_prep_w1t(const float* __restrict__ W1,
                           unsigned short* __restrict__ Bpk) {
  int t = blockIdx.x * blockDim.x + threadIdx.x;  // t = k*256+n
  if (t >= 512 * 256) return;
  int k = t >> 8, n = t & 255;
  unsigned short hi, lo;
  split_bf16(W1[t], hi, lo);
  int ks = k >> 5, quad = (k >> 3) & 3, j = k & 7;
  int nt = n >> 4, lane = quad * 16 + (n & 15);
  size_t ehi = ((size_t)(ks * 16 + nt) * 2) * 64 + lane;
  Bpk[ehi * 8 + j] = hi;
  Bpk[(ehi + 64) * 8 + j] = lo;
}

// -------- GEMM1: hs = (f16) dinv ⊙ (x @ W1) --------------------------------
// wave-tile: 32 rows x 64 cols; block = 4 waves = 32 rows x 256 cols.
// True ping-pong double-buffer: launch_bounds(256,3) opens ~170 VGPRs so the
// two B/A stages live in registers (R7 @60 VGPR: compiler serialized it).
__global__ __launch_bounds__(256, 3) void k_gemm_mfma(
    const float* __restrict__ A,     // [M,512]
    const uint4* __restrict__ Bpk,   // packed, 32768 uint4 (512 KB, L2-hot)
    const float* __restrict__ dinv,  // [M]
    f16* __restrict__ C,             // [M,256] scaled output
    int M) {
  const int K = 512;
  const int cg = threadIdx.x >> 6;     // col group: nt = cg*4 .. cg*4+3
  const int lane = threadIdx.x & 63;
  const int quad = lane >> 4;
  const int l16 = lane & 15;

  const int m0 = blockIdx.x * 32;
  int r0 = m0 + l16;
  int r1 = m0 + 16 + l16;
  const float* a0p = A + (size_t)(r0 < M ? r0 : M - 1) * K;
  const float* a1p = A + (size_t)(r1 < M ? r1 : M - 1) * K;

  floatx4 acc[2][4];
#pragma unroll
  for (int f = 0; f < 2; ++f)
#pragma unroll
    for (int t = 0; t < 4; ++t) acc[f][t] = (floatx4){0.f, 0.f, 0.f, 0.f};

  const uint4* bp0 = Bpk + lane + (size_t)(cg * 4) * 128;

  // ping-pong stages (indices constant-fold under unroll 2)
  float4 ax[2][2], ay[2][2];
  BF8 bh[2][4], bl[2][4];

  ax[0][0] = *(const float4*)(a0p + quad * 8);
  ax[0][1] = *(const float4*)(a0p + quad * 8 + 4);
  ay[0][0] = *(const float4*)(a1p + quad * 8);
  ay[0][1] = *(const float4*)(a1p + quad * 8 + 4);
#pragma unroll
  for (int t = 0; t < 4; ++t) {
    bh[0][t].q = bp0[t * 128];
    bl[0][t].q = bp0[t * 128 + 64];
  }

#pragma unroll 2
  for (int ks = 0; ks < 16; ++ks) {
    const int cur = ks & 1;
    const int nxt = cur ^ 1;

    // issue next stage's loads first (cover with this stage's VALU+MFMA)
    if (ks < 15) {
      const int kb = (ks + 1) * 32 + quad * 8;
      ax[nxt][0] = *(const float4*)(a0p + kb);
      ax[nxt][1] = *(const float4*)(a0p + kb + 4);
      ay[nxt][0] = *(const float4*)(a1p + kb);
      ay[nxt][1] = *(const float4*)(a1p + kb + 4);
      const uint4* np = bp0 + (size_t)(ks + 1) * 2048;
#pragma unroll
      for (int t = 0; t < 4; ++t) {
        bh[nxt][t].q = np[t * 128];
        bl[nxt][t].q = np[t * 128 + 64];
      }
    }

    // convert current A to hi/lo bf16
    BF8 ahi0, alo0, ahi1, alo1;
    {
      float xv[8] = {ax[cur][0].x, ax[cur][0].y, ax[cur][0].z, ax[cur][0].w,
                     ax[cur][1].x, ax[cur][1].y, ax[cur][1].z, ax[cur][1].w};
      float yv[8] = {ay[cur][0].x, ay[cur][0].y, ay[cur][0].z, ay[cur][0].w,
                     ay[cur][1].x, ay[cur][1].y, ay[cur][1].z, ay[cur][1].w};
#pragma unroll
      for (int j = 0; j < 8; ++j) {
        split_bf16(xv[j], ahi0.u[j], alo0.u[j]);
        split_bf16(yv[j], ahi1.u[j], alo1.u[j]);
      }
    }

#pragma unroll
    for (int t = 0; t < 4; ++t) {
      acc[0][t] = __builtin_amdgcn_mfma_f32_16x16x32_bf16(ahi0.v, bh[cur][t].v, acc[0][t], 0, 0, 0);
      acc[0][t] = __builtin_amdgcn_mfma_f32_16x16x32_bf16(alo0.v, bh[cur][t].v, acc[0][t], 0, 0, 0);
      acc[0][t] = __builtin_amdgcn_mfma_f32_16x16x32_bf16(ahi0.v, bl[cur][t].v, acc[0][t], 0, 0, 0);
      acc[1][t] = __builtin_amdgcn_mfma_f32_16x16x32_bf16(ahi1.v, bh[cur][t].v, acc[1][t], 0, 0, 0);
      acc[1][t] = __builtin_amdgcn_mfma_f32_16x16x32_bf16(alo1.v, bh[cur][t].v, acc[1][t], 0, 0, 0);
      acc[1][t] = __builtin_amdgcn_mfma_f32_16x16x32_bf16(ahi1.v, bl[cur][t].v, acc[1][t], 0, 0, 0);
    }
  }

  // store hs = dinv[row] * acc; C/D layout col=lane&15, row=quad*4+reg
#pragma unroll
  for (int f = 0; f < 2; ++f)
#pragma unroll
    for (int r = 0; r < 4; ++r) {
      int gm = m0 + f * 16 + quad * 4 + r;
      if (gm < M) {
        float dv = dinv[gm];
#pragma unroll
        for (int t = 0; t < 4; ++t) {
          const int col = (cg * 4 + t) * 16 + l16;
          C[(size_t)gm * 256 + col] = (f16)(dv * acc[f][t][r]);
        }
      }
    }
}

// ------- fused gather1 + (+b1 -> elu -> dropout -> dot W2) -----------------
// hs is pre-scaled by dinv. agg[d] = dd*(hs[d] + Σ hs[s]).
// one wave serves TWO nodes (half-wave each); lane covers 8 fp16 feats (16B).
// stores zs[d] = dd * z[d] (pre-scaled for layer-2 gather).
__global__ __launch_bounds__(256) void k_gather_fused(
    const int* __restrict__ rowptr, const int* __restrict__ csr_src,
    const float* __restrict__ dinv, const f16* __restrict__ hs,
    const float* __restrict__ b1, const float* __restrict__ W2,
    float* __restrict__ zs, int N) {
  int wave = (blockIdx.x * blockDim.x + threadIdx.x) >> 6;
  int lane = threadIdx.x & 63;
  int half = lane >> 5;
  int l = lane & 31;
  int d = wave * 2 + half;
  bool valid = d < N;
  if (!valid) d = N - 1;
  float dd = dinv[d];
  int beg = rowptr[d], end = rowptr[d + 1];
  int f0 = l << 3;  // 8 features per lane

  float acc[8];
  {
    F16x8 hv;
    hv.q = *(const uint4*)(hs + ((size_t)d << 8) + f0);
#pragma unroll
    for (int i = 0; i < 8; ++i) acc[i] = (float)hv.v[i];
  }

  int e = beg;
  for (; e + 3 < end; e += 4) {
    int s0 = csr_src[e], s1 = csr_src[e + 1], s2 = csr_src[e + 2], s3 = csr_src[e + 3];
    F16x8 a, b, c, dq;
    a.q = *(const uint4*)(hs + ((size_t)s0 << 8) + f0);
    b.q = *(const uint4*)(hs + ((size_t)s1 << 8) + f0);
    c.q = *(const uint4*)(hs + ((size_t)s2 << 8) + f0);
    dq.q = *(const uint4*)(hs + ((size_t)s3 << 8) + f0);
#pragma unroll
    for (int i = 0; i < 8; ++i)
      acc[i] += (float)a.v[i] + (float)b.v[i] + (float)c.v[i] + (float)dq.v[i];
  }
  for (; e < end; ++e) {
    int s0 = csr_src[e];
    F16x8 a;
    a.q = *(const uint4*)(hs + ((size_t)s0 << 8) + f0);
#pragma unroll
    for (int i = 0; i < 8; ++i) acc[i] += (float)a.v[i];
  }

  // epilogue: scale by dd, bias, elu, threefry dropout, dot W2
  float4 bb0 = *(const float4*)(b1 + f0);
  float4 bb1 = *(const float4*)(b1 + f0 + 4);
  float4 w0  = *(const float4*)(W2 + f0);
  float4 w1  = *(const float4*)(W2 + f0 + 4);
  const float* bbp[8] = {&bb0.x, &bb0.y, &bb0.z, &bb0.w, &bb1.x, &bb1.y, &bb1.z, &bb1.w};
  const float* wp[8]  = {&w0.x, &w0.y, &w0.z, &w0.w, &w1.x, &w1.y, &w1.z, &w1.w};

  float sum = 0.f;
  uint32_t jbase = ((uint32_t)d << 8) + (uint32_t)f0;
#pragma unroll
  for (int i = 0; i < 8; ++i) {
    uint32_t r0, r1;
    threefry_0_42(0u, jbase + i, r0, r1);  // ctr = (hi=0, lo=j)
    uint32_t bits = r0 ^ r1;
    float u = __uint_as_float((bits >> 9) | 0x3f800000u) - 1.0f;
    float va = dd * acc[i] + *bbp[i];
    float ea = va > 0.f ? va : expm1f(va);
    float ha = (u < 0.75f) ? (ea * (1.0f / 0.75f)) : 0.f;
    sum += ha * *wp[i];
  }
#pragma unroll
  for (int off = 16; off > 0; off >>= 1) sum += __shfl_down(sum, off, 32);
  if (l == 0 && valid) zs[d] = dd * sum;
}

// ------- gather layer 2: out[d] = b2 + dd*(zs[d] + Σ zs[s]) ----------------
// 4 nodes per wave (16 lanes each; avg degree ~16)
__global__ __launch_bounds__(256) void k_gather2(
    const int* __restrict__ rowptr, const int* __restrict__ csr_src,
    const float* __restrict__ dinv, const float* __restrict__ zs,
    const float* __restrict__ b2, float* __restrict__ out, int N) {
  int wave = (blockIdx.x * blockDim.x + threadIdx.x) >> 6;
  int lane = threadIdx.x & 63;
  int sub = lane >> 4;   // 0..3
  int l = lane & 15;
  int d = wave * 4 + sub;
  bool valid = d < N;
  if (!valid) d = N - 1;
  float dd = dinv[d];
  int beg = rowptr[d], end = rowptr[d + 1];

  float acc = 0.f;
  for (int e = beg + l; e < end; e += 16) {
    acc += zs[csr_src[e]];
  }
#pragma unroll
  for (int off = 8; off > 0; off >>= 1) acc += __shfl_down(acc, off, 16);
  if (l == 0 && valid) out[d] = b2[0] + dd * (zs[d] + acc);
}

// ---------------------------------------------------------------------------
extern "C" void kernel_launch(void* const* d_in, const int* in_sizes, int n_in,
                              void* d_out, int out_size, void* d_ws, size_t ws_size,
                              hipStream_t stream) {
  const float* x  = (const float*)d_in[0];
  const int*   ei = (const int*)d_in[1];   // [2,E] int32
  const float* W1 = (const float*)d_in[2];
  const float* b1 = (const float*)d_in[3];
  const float* W2 = (const float*)d_in[4];
  const float* b2 = (const float*)d_in[5];
  float* out = (float*)d_out;

  const int E = in_sizes[1] / 2;
  const int N = in_sizes[0] / 512;  // 50000
  const int* src = ei;
  const int* dst = ei + E;

  char* ws = (char*)d_ws;
  size_t off = 0;
  auto alloc = [&](size_t bytes) -> void* {
    void* p = ws + off;
    off += (bytes + 255) & ~(size_t)255;
    return p;
  };
  int*   deg     = (int*)  alloc((size_t)N * 4);
  int*   rowptr  = (int*)  alloc((size_t)(N + 1) * 4);
  int*   cursor  = (int*)  alloc((size_t)N * 4);
  int*   csr_src = (int*)  alloc((size_t)E * 4);          // 3.2 MB
  int*   sums    = (int*)  alloc(1024 * 4);
  float* dinv    = (float*)alloc((size_t)N * 4);
  f16*   hs      = (f16*)  alloc((size_t)N * 256 * 2);    // 25.6 MB
  float* zs      = (float*)alloc((size_t)N * 4);
  uint4* Bpk     = (uint4*)alloc(32768 * 16);             // 512 KB packed W1T

  const int nb = (N + 255) / 256;  // scan blocks

  hipMemsetAsync(deg, 0, (size_t)N * 4, stream);
  k_prep_w1t<<<(512 * 256 + 255) / 256, 256, 0, stream>>>(W1, (unsigned short*)Bpk);
  k_deg<<<(E + 255) / 256, 256, 0, stream>>>(dst, E, deg);
  k_scan1<<<nb, 256, 0, stream>>>(deg, rowptr, sums, dinv, N);
  k_scan2<<<1, 1024, 0, stream>>>(sums, nb);
  k_scan3<<<(N + 255) / 256, 256, 0, stream>>>(rowptr, cursor, sums, N, E);
  k_bucket<<<(E + 255) / 256, 256, 0, stream>>>(src, dst, cursor, csr_src, E);

  k_gemm_mfma<<<(N + 31) / 32, 256, 0, stream>>>(x, Bpk, dinv, hs, N);

  const int nwaves1 = (N + 1) / 2;  // 2 nodes per wave
  k_gather_fused<<<(nwaves1 * 64 + 255) / 256, 256, 0, stream>>>(rowptr, csr_src, dinv, hs,
                                                                 b1, W2, zs, N);
  const int nwaves2 = (N + 3) / 4;  // 4 nodes per wave
  k_gather2<<<(nwaves2 * 64 + 255) / 256, 256, 0, stream>>>(rowptr, csr_src, dinv, zs, b2, out, N);
}

// Round 9
// 366.215 us; speedup vs baseline: 2.1367x; 2.1367x over previous
//
#include <hip/hip_runtime.h>
#include <stdint.h>

// ---------------------------------------------------------------------------
// GCN 2-layer: out = Ahat( dropout(elu( Ahat(x@W1)+b1 )) @ W2 ) + b2
// Ahat = D^-1/2 (A+I) D^-1/2
// dropout = jax threefry2x32 key(42), p=0.25, partitionable path.
// R8->R9: GEMM rebuilt m97-style: 64x256 block tile, A staged in LDS
// (double-buffered, coalesced, shared by 4 waves -> 4x fewer A transactions),
// wave tile 64x64 (B:MFMA ratio halved). NO __launch_bounds__ min-waves
// (R8: arg2=3 forced VGPR=40 -> scratch spill disaster, 512 us).
// ---------------------------------------------------------------------------

typedef __bf16 bf16x8 __attribute__((ext_vector_type(8)));
typedef float floatx4 __attribute__((ext_vector_type(4)));
typedef _Float16 f16;
typedef _Float16 f16x8 __attribute__((ext_vector_type(8)));

union BF8 {
  bf16x8 v;
  unsigned short u[8];
  uint4 q;
};

union F16x8 {
  f16x8 v;
  uint4 q;
};

// ---------------- Threefry-2x32, key = (0, 42), 20 rounds ------------------
__device__ __forceinline__ void tf_round(uint32_t& x0, uint32_t& x1, int r) {
  x0 += x1;
  x1 = (x1 << r) | (x1 >> (32 - r));
  x1 ^= x0;
}

__device__ __forceinline__ void threefry_0_42(uint32_t c0, uint32_t c1,
                                              uint32_t& o0, uint32_t& o1) {
  const uint32_t ks0 = 0u;
  const uint32_t ks1 = 42u;
  const uint32_t ks2 = 0x1BD11BDAu ^ 0u ^ 42u;
  uint32_t x0 = c0 + ks0;
  uint32_t x1 = c1 + ks1;
  tf_round(x0, x1, 13); tf_round(x0, x1, 15); tf_round(x0, x1, 26); tf_round(x0, x1, 6);
  x0 += ks1; x1 += ks2 + 1u;
  tf_round(x0, x1, 17); tf_round(x0, x1, 29); tf_round(x0, x1, 16); tf_round(x0, x1, 24);
  x0 += ks2; x1 += ks0 + 2u;
  tf_round(x0, x1, 13); tf_round(x0, x1, 15); tf_round(x0, x1, 26); tf_round(x0, x1, 6);
  x0 += ks0; x1 += ks1 + 3u;
  tf_round(x0, x1, 17); tf_round(x0, x1, 29); tf_round(x0, x1, 16); tf_round(x0, x1, 24);
  x0 += ks1; x1 += ks2 + 4u;
  tf_round(x0, x1, 13); tf_round(x0, x1, 15); tf_round(x0, x1, 26); tf_round(x0, x1, 6);
  x0 += ks2; x1 += ks0 + 5u;
  o0 = x0; o1 = x1;
}

// split fp32 -> bf16 hi (truncate) + bf16 lo (truncate of residual)
__device__ __forceinline__ void split_bf16(float x, unsigned short& hi, unsigned short& lo) {
  uint32_t b = __float_as_uint(x);
  hi = (unsigned short)(b >> 16);
  float hif = __uint_as_float(b & 0xffff0000u);
  float lof = x - hif;  // exact
  lo = (unsigned short)(__float_as_uint(lof) >> 16);
}

// ---------------- degree -----------------------------------------------
__global__ void k_deg(const int* __restrict__ dst, int E, int* __restrict__ deg) {
  int e = blockIdx.x * blockDim.x + threadIdx.x;
  if (e < E) atomicAdd(&deg[dst[e]], 1);
}

// ---------------- 3-phase exclusive scan (+ dinv fused) --------------------
__global__ __launch_bounds__(256) void k_scan1(const int* __restrict__ deg,
                                               int* __restrict__ excl,
                                               int* __restrict__ sums,
                                               float* __restrict__ dinv, int N) {
  __shared__ int sm[256];
  int tid = threadIdx.x;
  int i = blockIdx.x * 256 + tid;
  int v = (i < N) ? deg[i] : 0;
  if (i < N) dinv[i] = 1.0f / sqrtf((float)(v + 1));  // +1 self loop
  sm[tid] = v;
  __syncthreads();
#pragma unroll
  for (int off = 1; off < 256; off <<= 1) {
    int t = (tid >= off) ? sm[tid - off] : 0;
    __syncthreads();
    sm[tid] += t;
    __syncthreads();
  }
  if (i < N) excl[i] = sm[tid] - v;
  if (tid == 255) sums[blockIdx.x] = sm[255];
}

__global__ __launch_bounds__(1024) void k_scan2(int* __restrict__ sums, int nb) {
  __shared__ int sm[1024];
  int tid = threadIdx.x;
  int v = (tid < nb) ? sums[tid] : 0;
  sm[tid] = v;
  __syncthreads();
#pragma unroll
  for (int off = 1; off < 1024; off <<= 1) {
    int t = (tid >= off) ? sm[tid - off] : 0;
    __syncthreads();
    sm[tid] += t;
    __syncthreads();
  }
  if (tid < nb) sums[tid] = sm[tid] - v;  // exclusive, in place
}

__global__ void k_scan3(int* __restrict__ rowptr, int* __restrict__ cursor,
                        const int* __restrict__ sums, int N, int E) {
  int i = blockIdx.x * blockDim.x + threadIdx.x;
  if (i < N) {
    int r = rowptr[i] + sums[i >> 8];
    rowptr[i] = r;
    cursor[i] = r;
  }
  if (i == 0) rowptr[N] = E;
}

// ---------------- bucket edges by dst --------------------------------------
__global__ void k_bucket(const int* __restrict__ src, const int* __restrict__ dst,
                         int* __restrict__ cursor, int* __restrict__ csr_src, int E) {
  int e = blockIdx.x * blockDim.x + threadIdx.x;
  if (e < E) {
    int pos = atomicAdd(&cursor[dst[e]], 1);
    csr_src[pos] = src[e];
  }
}

// -------- prep: W1 [512][256] fp32 -> packed fragment-major bf16 hi/lo -----
// uint4 entry index = ((ks*16 + nt)*2 + plane)*64 + lane;
// lane = quad*16 + (n&15), k = ks*32 + quad*8 + j, nt = n>>4.
__global__ void k_prep_w1t(const float* __restrict__ W1,
                           unsigned short* __restrict__ Bpk) {
  int t = blockIdx.x * blockDim.x + threadIdx.x;  // t = k*256+n
  if (t >= 512 * 256) return;
  int k = t >> 8, n = t & 255;
  unsigned short hi, lo;
  split_bf16(W1[t], hi, lo);
  int ks = k >> 5, quad = (k >> 3) & 3, j = k & 7;
  int nt = n >> 4, lane = quad * 16 + (n & 15);
  size_t ehi = ((size_t)(ks * 16 + nt) * 2) * 64 + lane;
  Bpk[ehi * 8 + j] = hi;
  Bpk[(ehi + 64) * 8 + j] = lo;
}

// -------- GEMM1: hs = (f16) dinv ⊙ (x @ W1) --------------------------------
// Block tile 64 rows x 256 cols, 4 waves (wave = 64 rows x 64 cols).
// A tile (64x32 fp32) staged in LDS, double-buffered, coalesced, shared by
// all 4 waves. B fragments direct from packed L2-hot global. 1 barrier/ks.
__global__ __launch_bounds__(256) void k_gemm_mfma(
    const float* __restrict__ A,     // [M,512]
    const uint4* __restrict__ Bpk,   // packed, 32768 uint4 (512 KB, L2-hot)
    const float* __restrict__ dinv,  // [M]
    f16* __restrict__ C,             // [M,256] scaled output
    int M) {
  __shared__ float As[2][64 * 36];   // 36-float row stride: 16B-aligned rows,
                                     // ds_read banks 2-way only (free)
  const int tid = threadIdx.x;
  const int cg = tid >> 6;           // wave id = column group (nt = cg*4..+3)
  const int lane = tid & 63;
  const int quad = lane >> 4;
  const int l16 = lane & 15;
  const int m0 = blockIdx.x * 64;

  // ---- staging assignment: thread t -> row t>>2, col-quad t&3 (8 floats) --
  const int srow = tid >> 2;
  const int scq = tid & 3;
  int grow = m0 + srow;
  if (grow >= M) grow = M - 1;
  const float* gsp = A + (size_t)grow * 512 + scq * 8;
  const int lws = srow * 36 + scq * 8;

  // stage ks=0
  {
    float4 s0 = *(const float4*)(gsp);
    float4 s1 = *(const float4*)(gsp + 4);
    *(float4*)&As[0][lws] = s0;
    *(float4*)&As[0][lws + 4] = s1;
  }
  __syncthreads();

  floatx4 acc[4][4];  // [row-frag][col-tile]
#pragma unroll
  for (int fr = 0; fr < 4; ++fr)
#pragma unroll
    for (int t = 0; t < 4; ++t) acc[fr][t] = (floatx4){0.f, 0.f, 0.f, 0.f};

  const uint4* bp0 = Bpk + lane + (size_t)(cg * 4) * 128;

  for (int ks = 0; ks < 16; ++ks) {
    const int cur = ks & 1;
    const int nxt = cur ^ 1;

    // issue next A-tile global loads (kept in flight across the MFMAs)
    float4 p0, p1;
    if (ks < 15) {
      p0 = *(const float4*)(gsp + (ks + 1) * 32);
      p1 = *(const float4*)(gsp + (ks + 1) * 32 + 4);
    }

    // B fragments for this ks (coalesced 1KB loads, L2-hot)
    const uint4* bp = bp0 + (size_t)ks * 2048;
    BF8 bh[4], bl[4];
#pragma unroll
    for (int t = 0; t < 4; ++t) {
      bh[t].q = bp[t * 128];
      bl[t].q = bp[t * 128 + 64];
    }

    // A fragments from LDS, convert, MFMA
#pragma unroll
    for (int fr = 0; fr < 4; ++fr) {
      const float* lr = &As[cur][(fr * 16 + l16) * 36 + quad * 8];
      float4 f0 = *(const float4*)lr;
      float4 f1 = *(const float4*)(lr + 4);
      BF8 ahi, alo;
      {
        float av[8] = {f0.x, f0.y, f0.z, f0.w, f1.x, f1.y, f1.z, f1.w};
#pragma unroll
        for (int j = 0; j < 8; ++j) split_bf16(av[j], ahi.u[j], alo.u[j]);
      }
#pragma unroll
      for (int t = 0; t < 4; ++t) {
        acc[fr][t] = __builtin_amdgcn_mfma_f32_16x16x32_bf16(ahi.v, bh[t].v, acc[fr][t], 0, 0, 0);
        acc[fr][t] = __builtin_amdgcn_mfma_f32_16x16x32_bf16(alo.v, bh[t].v, acc[fr][t], 0, 0, 0);
        acc[fr][t] = __builtin_amdgcn_mfma_f32_16x16x32_bf16(ahi.v, bl[t].v, acc[fr][t], 0, 0, 0);
      }
    }

    // write next tile, then barrier
    if (ks < 15) {
      *(float4*)&As[nxt][lws] = p0;
      *(float4*)&As[nxt][lws + 4] = p1;
    }
    __syncthreads();
  }

  // store hs = dinv[row] * acc; C/D layout col=lane&15, row=quad*4+reg
#pragma unroll
  for (int fr = 0; fr < 4; ++fr)
#pragma unroll
    for (int r = 0; r < 4; ++r) {
      int gm = m0 + fr * 16 + quad * 4 + r;
      if (gm < M) {
        float dv = dinv[gm];
#pragma unroll
        for (int t = 0; t < 4; ++t) {
          const int col = (cg * 4 + t) * 16 + l16;
          C[(size_t)gm * 256 + col] = (f16)(dv * acc[fr][t][r]);
        }
      }
    }
}

// ------- fused gather1 + (+b1 -> elu -> dropout -> dot W2) -----------------
// hs is pre-scaled by dinv. agg[d] = dd*(hs[d] + Σ hs[s]).
// one wave serves TWO nodes (half-wave each); lane covers 8 fp16 feats (16B).
// stores zs[d] = dd * z[d] (pre-scaled for layer-2 gather).
__global__ __launch_bounds__(256) void k_gather_fused(
    const int* __restrict__ rowptr, const int* __restrict__ csr_src,
    const float* __restrict__ dinv, const f16* __restrict__ hs,
    const float* __restrict__ b1, const float* __restrict__ W2,
    float* __restrict__ zs, int N) {
  int wave = (blockIdx.x * blockDim.x + threadIdx.x) >> 6;
  int lane = threadIdx.x & 63;
  int half = lane >> 5;
  int l = lane & 31;
  int d = wave * 2 + half;
  bool valid = d < N;
  if (!valid) d = N - 1;
  float dd = dinv[d];
  int beg = rowptr[d], end = rowptr[d + 1];
  int f0 = l << 3;  // 8 features per lane

  float acc[8];
  {
    F16x8 hv;
    hv.q = *(const uint4*)(hs + ((size_t)d << 8) + f0);
#pragma unroll
    for (int i = 0; i < 8; ++i) acc[i] = (float)hv.v[i];
  }

  int e = beg;
  for (; e + 3 < end; e += 4) {
    int s0 = csr_src[e], s1 = csr_src[e + 1], s2 = csr_src[e + 2], s3 = csr_src[e + 3];
    F16x8 a, b, c, dq;
    a.q = *(const uint4*)(hs + ((size_t)s0 << 8) + f0);
    b.q = *(const uint4*)(hs + ((size_t)s1 << 8) + f0);
    c.q = *(const uint4*)(hs + ((size_t)s2 << 8) + f0);
    dq.q = *(const uint4*)(hs + ((size_t)s3 << 8) + f0);
#pragma unroll
    for (int i = 0; i < 8; ++i)
      acc[i] += (float)a.v[i] + (float)b.v[i] + (float)c.v[i] + (float)dq.v[i];
  }
  for (; e < end; ++e) {
    int s0 = csr_src[e];
    F16x8 a;
    a.q = *(const uint4*)(hs + ((size_t)s0 << 8) + f0);
#pragma unroll
    for (int i = 0; i < 8; ++i) acc[i] += (float)a.v[i];
  }

  // epilogue: scale by dd, bias, elu, threefry dropout, dot W2
  float4 bb0 = *(const float4*)(b1 + f0);
  float4 bb1 = *(const float4*)(b1 + f0 + 4);
  float4 w0  = *(const float4*)(W2 + f0);
  float4 w1  = *(const float4*)(W2 + f0 + 4);
  const float* bbp[8] = {&bb0.x, &bb0.y, &bb0.z, &bb0.w, &bb1.x, &bb1.y, &bb1.z, &bb1.w};
  const float* wp[8]  = {&w0.x, &w0.y, &w0.z, &w0.w, &w1.x, &w1.y, &w1.z, &w1.w};

  float sum = 0.f;
  uint32_t jbase = ((uint32_t)d << 8) + (uint32_t)f0;
#pragma unroll
  for (int i = 0; i < 8; ++i) {
    uint32_t r0, r1;
    threefry_0_42(0u, jbase + i, r0, r1);  // ctr = (hi=0, lo=j)
    uint32_t bits = r0 ^ r1;
    float u = __uint_as_float((bits >> 9) | 0x3f800000u) - 1.0f;
    float va = dd * acc[i] + *bbp[i];
    float ea = va > 0.f ? va : expm1f(va);
    float ha = (u < 0.75f) ? (ea * (1.0f / 0.75f)) : 0.f;
    sum += ha * *wp[i];
  }
#pragma unroll
  for (int off = 16; off > 0; off >>= 1) sum += __shfl_down(sum, off, 32);
  if (l == 0 && valid) zs[d] = dd * sum;
}

// ------- gather layer 2: out[d] = b2 + dd*(zs[d] + Σ zs[s]) ----------------
// 4 nodes per wave (16 lanes each; avg degree ~16)
__global__ __launch_bounds__(256) void k_gather2(
    const int* __restrict__ rowptr, const int* __restrict__ csr_src,
    const float* __restrict__ dinv, const float* __restrict__ zs,
    const float* __restrict__ b2, float* __restrict__ out, int N) {
  int wave = (blockIdx.x * blockDim.x + threadIdx.x) >> 6;
  int lane = threadIdx.x & 63;
  int sub = lane >> 4;   // 0..3
  int l = lane & 15;
  int d = wave * 4 + sub;
  bool valid = d < N;
  if (!valid) d = N - 1;
  float dd = dinv[d];
  int beg = rowptr[d], end = rowptr[d + 1];

  float acc = 0.f;
  for (int e = beg + l; e < end; e += 16) {
    acc += zs[csr_src[e]];
  }
#pragma unroll
  for (int off = 8; off > 0; off >>= 1) acc += __shfl_down(acc, off, 16);
  if (l == 0 && valid) out[d] = b2[0] + dd * (zs[d] + acc);
}

// ---------------------------------------------------------------------------
extern "C" void kernel_launch(void* const* d_in, const int* in_sizes, int n_in,
                              void* d_out, int out_size, void* d_ws, size_t ws_size,
                              hipStream_t stream) {
  const float* x  = (const float*)d_in[0];
  const int*   ei = (const int*)d_in[1];   // [2,E] int32
  const float* W1 = (const float*)d_in[2];
  const float* b1 = (const float*)d_in[3];
  const float* W2 = (const float*)d_in[4];
  const float* b2 = (const float*)d_in[5];
  float* out = (float*)d_out;

  const int E = in_sizes[1] / 2;
  const int N = in_sizes[0] / 512;  // 50000
  const int* src = ei;
  const int* dst = ei + E;

  char* ws = (char*)d_ws;
  size_t off = 0;
  auto alloc = [&](size_t bytes) -> void* {
    void* p = ws + off;
    off += (bytes + 255) & ~(size_t)255;
    return p;
  };
  int*   deg     = (int*)  alloc((size_t)N * 4);
  int*   rowptr  = (int*)  alloc((size_t)(N + 1) * 4);
  int*   cursor  = (int*)  alloc((size_t)N * 4);
  int*   csr_src = (int*)  alloc((size_t)E * 4);          // 3.2 MB
  int*   sums    = (int*)  alloc(1024 * 4);
  float* dinv    = (float*)alloc((size_t)N * 4);
  f16*   hs      = (f16*)  alloc((size_t)N * 256 * 2);    // 25.6 MB
  float* zs      = (float*)alloc((size_t)N * 4);
  uint4* Bpk     = (uint4*)alloc(32768 * 16);             // 512 KB packed W1T

  const int nb = (N + 255) / 256;  // scan blocks

  hipMemsetAsync(deg, 0, (size_t)N * 4, stream);
  k_prep_w1t<<<(512 * 256 + 255) / 256, 256, 0, stream>>>(W1, (unsigned short*)Bpk);
  k_deg<<<(E + 255) / 256, 256, 0, stream>>>(dst, E, deg);
  k_scan1<<<nb, 256, 0, stream>>>(deg, rowptr, sums, dinv, N);
  k_scan2<<<1, 1024, 0, stream>>>(sums, nb);
  k_scan3<<<(N + 255) / 256, 256, 0, stream>>>(rowptr, cursor, sums, N, E);
  k_bucket<<<(E + 255) / 256, 256, 0, stream>>>(src, dst, cursor, csr_src, E);

  k_gemm_mfma<<<(N + 63) / 64, 256, 0, stream>>>(x, Bpk, dinv, hs, N);

  const int nwaves1 = (N + 1) / 2;  // 2 nodes per wave
  k_gather_fused<<<(nwaves1 * 64 + 255) / 256, 256, 0, stream>>>(rowptr, csr_src, dinv, hs,
                                                                 b1, W2, zs, N);
  const int nwaves2 = (N + 3) / 4;  // 4 nodes per wave
  k_gather2<<<(nwaves2 * 64 + 255) / 256, 256, 0, stream>>>(rowptr, csr_src, dinv, zs, b2, out, N);
}

// Round 10
// 363.450 us; speedup vs baseline: 2.1530x; 1.0076x over previous
//
#include <hip/hip_runtime.h>
#include <stdint.h>

// ---------------------------------------------------------------------------
// GCN 2-layer: out = Ahat( dropout(elu( Ahat(x@W1)+b1 )) @ W2 ) + b2
// Ahat = D^-1/2 (A+I) D^-1/2
// dropout = jax threefry2x32 key(42), p=0.25, partitionable path.
// R9->R10: GEMM switched to SINGLE fp16 MFMA (error budget allows: ~3e-4 RMS
// added vs 5.98e-3 threshold). A staged to LDS as fp16 (converted once at
// staging -> kills per-wave in-loop split VALU, R9's hidden cost), B packed
// as one fp16 plane (256 KB, L2-hot). 16 MFMA/ks/wave instead of 48.
// ---------------------------------------------------------------------------

typedef float floatx4 __attribute__((ext_vector_type(4)));
typedef _Float16 f16;
typedef _Float16 f16x8 __attribute__((ext_vector_type(8)));

union F16x8 {
  f16x8 v;
  f16 e[8];
  uint4 q;
};

// ---------------- Threefry-2x32, key = (0, 42), 20 rounds ------------------
__device__ __forceinline__ void tf_round(uint32_t& x0, uint32_t& x1, int r) {
  x0 += x1;
  x1 = (x1 << r) | (x1 >> (32 - r));
  x1 ^= x0;
}

__device__ __forceinline__ void threefry_0_42(uint32_t c0, uint32_t c1,
                                              uint32_t& o0, uint32_t& o1) {
  const uint32_t ks0 = 0u;
  const uint32_t ks1 = 42u;
  const uint32_t ks2 = 0x1BD11BDAu ^ 0u ^ 42u;
  uint32_t x0 = c0 + ks0;
  uint32_t x1 = c1 + ks1;
  tf_round(x0, x1, 13); tf_round(x0, x1, 15); tf_round(x0, x1, 26); tf_round(x0, x1, 6);
  x0 += ks1; x1 += ks2 + 1u;
  tf_round(x0, x1, 17); tf_round(x0, x1, 29); tf_round(x0, x1, 16); tf_round(x0, x1, 24);
  x0 += ks2; x1 += ks0 + 2u;
  tf_round(x0, x1, 13); tf_round(x0, x1, 15); tf_round(x0, x1, 26); tf_round(x0, x1, 6);
  x0 += ks0; x1 += ks1 + 3u;
  tf_round(x0, x1, 17); tf_round(x0, x1, 29); tf_round(x0, x1, 16); tf_round(x0, x1, 24);
  x0 += ks1; x1 += ks2 + 4u;
  tf_round(x0, x1, 13); tf_round(x0, x1, 15); tf_round(x0, x1, 26); tf_round(x0, x1, 6);
  x0 += ks2; x1 += ks0 + 5u;
  o0 = x0; o1 = x1;
}

// ---------------- degree -----------------------------------------------
__global__ void k_deg(const int* __restrict__ dst, int E, int* __restrict__ deg) {
  int e = blockIdx.x * blockDim.x + threadIdx.x;
  if (e < E) atomicAdd(&deg[dst[e]], 1);
}

// ---------------- 3-phase exclusive scan (+ dinv fused) --------------------
__global__ __launch_bounds__(256) void k_scan1(const int* __restrict__ deg,
                                               int* __restrict__ excl,
                                               int* __restrict__ sums,
                                               float* __restrict__ dinv, int N) {
  __shared__ int sm[256];
  int tid = threadIdx.x;
  int i = blockIdx.x * 256 + tid;
  int v = (i < N) ? deg[i] : 0;
  if (i < N) dinv[i] = 1.0f / sqrtf((float)(v + 1));  // +1 self loop
  sm[tid] = v;
  __syncthreads();
#pragma unroll
  for (int off = 1; off < 256; off <<= 1) {
    int t = (tid >= off) ? sm[tid - off] : 0;
    __syncthreads();
    sm[tid] += t;
    __syncthreads();
  }
  if (i < N) excl[i] = sm[tid] - v;
  if (tid == 255) sums[blockIdx.x] = sm[255];
}

__global__ __launch_bounds__(1024) void k_scan2(int* __restrict__ sums, int nb) {
  __shared__ int sm[1024];
  int tid = threadIdx.x;
  int v = (tid < nb) ? sums[tid] : 0;
  sm[tid] = v;
  __syncthreads();
#pragma unroll
  for (int off = 1; off < 1024; off <<= 1) {
    int t = (tid >= off) ? sm[tid - off] : 0;
    __syncthreads();
    sm[tid] += t;
    __syncthreads();
  }
  if (tid < nb) sums[tid] = sm[tid] - v;  // exclusive, in place
}

__global__ void k_scan3(int* __restrict__ rowptr, int* __restrict__ cursor,
                        const int* __restrict__ sums, int N, int E) {
  int i = blockIdx.x * blockDim.x + threadIdx.x;
  if (i < N) {
    int r = rowptr[i] + sums[i >> 8];
    rowptr[i] = r;
    cursor[i] = r;
  }
  if (i == 0) rowptr[N] = E;
}

// ---------------- bucket edges by dst --------------------------------------
__global__ void k_bucket(const int* __restrict__ src, const int* __restrict__ dst,
                         int* __restrict__ cursor, int* __restrict__ csr_src, int E) {
  int e = blockIdx.x * blockDim.x + threadIdx.x;
  if (e < E) {
    int pos = atomicAdd(&cursor[dst[e]], 1);
    csr_src[pos] = src[e];
  }
}

// -------- prep: W1 [512][256] fp32 -> packed fragment-major fp16 -----------
// uint4 entry index = (ks*16 + nt)*64 + lane; 8 fp16 each.
// lane = quad*16 + (n&15), k = ks*32 + quad*8 + j, nt = n>>4.
__global__ void k_prep_w1t(const float* __restrict__ W1,
                           f16* __restrict__ Bpk) {
  int t = blockIdx.x * blockDim.x + threadIdx.x;  // t = k*256+n
  if (t >= 512 * 256) return;
  int k = t >> 8, n = t & 255;
  int ks = k >> 5, quad = (k >> 3) & 3, j = k & 7;
  int nt = n >> 4, lane = quad * 16 + (n & 15);
  size_t e = ((size_t)(ks * 16 + nt)) * 64 + lane;
  Bpk[e * 8 + j] = (f16)W1[t];
}

// -------- GEMM1: hs = (f16) dinv ⊙ (x @ W1), single fp16 MFMA --------------
// Block tile 64 rows x 256 cols, 4 waves (wave = 64 rows x 64 cols).
// A tile converted to fp16 at staging time (no in-loop conversion), LDS
// double-buffered (2 x 64 x 40 fp16 = 10 KB). B single fp16 plane, L2-hot.
__global__ __launch_bounds__(256) void k_gemm_mfma(
    const float* __restrict__ A,     // [M,512]
    const uint4* __restrict__ Bpk,   // packed fp16, 16384 uint4 (256 KB)
    const float* __restrict__ dinv,  // [M]
    f16* __restrict__ C,             // [M,256] scaled output
    int M) {
  __shared__ f16 As[2][64 * 40];     // row stride 40 fp16 = 80 B (16B-aligned)
  const int tid = threadIdx.x;
  const int cg = tid >> 6;           // wave id = column group (nt = cg*4..+3)
  const int lane = tid & 63;
  const int quad = lane >> 4;
  const int l16 = lane & 15;
  const int m0 = blockIdx.x * 64;

  // ---- staging: thread t -> row t>>2, col-quad t&3 (8 floats -> 8 fp16) ---
  const int srow = tid >> 2;
  const int scq = tid & 3;
  int grow = m0 + srow;
  if (grow >= M) grow = M - 1;
  const float* gsp = A + (size_t)grow * 512 + scq * 8;
  f16* lwp = &As[0][srow * 40 + scq * 8];
  const int lstride = 64 * 40;       // buffer stride in f16

  auto cvt8 = [](float4 a, float4 b) {
    F16x8 r;
    r.e[0] = (f16)a.x; r.e[1] = (f16)a.y; r.e[2] = (f16)a.z; r.e[3] = (f16)a.w;
    r.e[4] = (f16)b.x; r.e[5] = (f16)b.y; r.e[6] = (f16)b.z; r.e[7] = (f16)b.w;
    return r;
  };

  // stage ks=0
  {
    float4 s0 = *(const float4*)(gsp);
    float4 s1 = *(const float4*)(gsp + 4);
    *(uint4*)lwp = cvt8(s0, s1).q;
  }
  __syncthreads();

  floatx4 acc[4][4];  // [row-frag][col-tile]
#pragma unroll
  for (int fr = 0; fr < 4; ++fr)
#pragma unroll
    for (int t = 0; t < 4; ++t) acc[fr][t] = (floatx4){0.f, 0.f, 0.f, 0.f};

  const uint4* bp0 = Bpk + lane + (size_t)(cg * 4) * 64;

  for (int ks = 0; ks < 16; ++ks) {
    const int cur = ks & 1;
    const int nxt = cur ^ 1;

    // issue next A-tile global loads (in flight across the MFMAs)
    float4 p0, p1;
    if (ks < 15) {
      p0 = *(const float4*)(gsp + (ks + 1) * 32);
      p1 = *(const float4*)(gsp + (ks + 1) * 32 + 4);
    }

    // B fragments for this ks (coalesced 1KB loads, L2-hot)
    const uint4* bp = bp0 + (size_t)ks * 1024;
    F16x8 bfrag[4];
#pragma unroll
    for (int t = 0; t < 4; ++t) bfrag[t].q = bp[t * 64];

    // A fragments from LDS (fp16, no conversion), MFMA
#pragma unroll
    for (int fr = 0; fr < 4; ++fr) {
      F16x8 af;
      af.q = *(const uint4*)&As[cur][(fr * 16 + l16) * 40 + quad * 8];
#pragma unroll
      for (int t = 0; t < 4; ++t) {
        acc[fr][t] = __builtin_amdgcn_mfma_f32_16x16x32_f16(af.v, bfrag[t].v, acc[fr][t], 0, 0, 0);
      }
    }

    // write next tile (converted), then barrier
    if (ks < 15) {
      *(uint4*)(lwp + nxt * lstride) = cvt8(p0, p1).q;
    }
    __syncthreads();
  }

  // store hs = dinv[row] * acc; C/D layout col=lane&15, row=quad*4+reg
#pragma unroll
  for (int fr = 0; fr < 4; ++fr)
#pragma unroll
    for (int r = 0; r < 4; ++r) {
      int gm = m0 + fr * 16 + quad * 4 + r;
      if (gm < M) {
        float dv = dinv[gm];
#pragma unroll
        for (int t = 0; t < 4; ++t) {
          const int col = (cg * 4 + t) * 16 + l16;
          C[(size_t)gm * 256 + col] = (f16)(dv * acc[fr][t][r]);
        }
      }
    }
}

// ------- fused gather1 + (+b1 -> elu -> dropout -> dot W2) -----------------
// hs is pre-scaled by dinv. agg[d] = dd*(hs[d] + Σ hs[s]).
// one wave serves TWO nodes (half-wave each); lane covers 8 fp16 feats (16B).
// stores zs[d] = dd * z[d] (pre-scaled for layer-2 gather).
__global__ __launch_bounds__(256) void k_gather_fused(
    const int* __restrict__ rowptr, const int* __restrict__ csr_src,
    const float* __restrict__ dinv, const f16* __restrict__ hs,
    const float* __restrict__ b1, const float* __restrict__ W2,
    float* __restrict__ zs, int N) {
  int wave = (blockIdx.x * blockDim.x + threadIdx.x) >> 6;
  int lane = threadIdx.x & 63;
  int half = lane >> 5;
  int l = lane & 31;
  int d = wave * 2 + half;
  bool valid = d < N;
  if (!valid) d = N - 1;
  float dd = dinv[d];
  int beg = rowptr[d], end = rowptr[d + 1];
  int f0 = l << 3;  // 8 features per lane

  float acc[8];
  {
    F16x8 hv;
    hv.q = *(const uint4*)(hs + ((size_t)d << 8) + f0);
#pragma unroll
    for (int i = 0; i < 8; ++i) acc[i] = (float)hv.e[i];
  }

  int e = beg;
  for (; e + 3 < end; e += 4) {
    int s0 = csr_src[e], s1 = csr_src[e + 1], s2 = csr_src[e + 2], s3 = csr_src[e + 3];
    F16x8 a, b, c, dq;
    a.q = *(const uint4*)(hs + ((size_t)s0 << 8) + f0);
    b.q = *(const uint4*)(hs + ((size_t)s1 << 8) + f0);
    c.q = *(const uint4*)(hs + ((size_t)s2 << 8) + f0);
    dq.q = *(const uint4*)(hs + ((size_t)s3 << 8) + f0);
#pragma unroll
    for (int i = 0; i < 8; ++i)
      acc[i] += (float)a.e[i] + (float)b.e[i] + (float)c.e[i] + (float)dq.e[i];
  }
  for (; e < end; ++e) {
    int s0 = csr_src[e];
    F16x8 a;
    a.q = *(const uint4*)(hs + ((size_t)s0 << 8) + f0);
#pragma unroll
    for (int i = 0; i < 8; ++i) acc[i] += (float)a.e[i];
  }

  // epilogue: scale by dd, bias, elu, threefry dropout, dot W2
  float4 bb0 = *(const float4*)(b1 + f0);
  float4 bb1 = *(const float4*)(b1 + f0 + 4);
  float4 w0  = *(const float4*)(W2 + f0);
  float4 w1  = *(const float4*)(W2 + f0 + 4);
  const float* bbp[8] = {&bb0.x, &bb0.y, &bb0.z, &bb0.w, &bb1.x, &bb1.y, &bb1.z, &bb1.w};
  const float* wp[8]  = {&w0.x, &w0.y, &w0.z, &w0.w, &w1.x, &w1.y, &w1.z, &w1.w};

  float sum = 0.f;
  uint32_t jbase = ((uint32_t)d << 8) + (uint32_t)f0;
#pragma unroll
  for (int i = 0; i < 8; ++i) {
    uint32_t r0, r1;
    threefry_0_42(0u, jbase + i, r0, r1);  // ctr = (hi=0, lo=j)
    uint32_t bits = r0 ^ r1;
    float u = __uint_as_float((bits >> 9) | 0x3f800000u) - 1.0f;
    float va = dd * acc[i] + *bbp[i];
    float ea = va > 0.f ? va : expm1f(va);
    float ha = (u < 0.75f) ? (ea * (1.0f / 0.75f)) : 0.f;
    sum += ha * *wp[i];
  }
#pragma unroll
  for (int off = 16; off > 0; off >>= 1) sum += __shfl_down(sum, off, 32);
  if (l == 0 && valid) zs[d] = dd * sum;
}

// ------- gather layer 2: out[d] = b2 + dd*(zs[d] + Σ zs[s]) ----------------
// 4 nodes per wave (16 lanes each; avg degree ~16)
__global__ __launch_bounds__(256) void k_gather2(
    const int* __restrict__ rowptr, const int* __restrict__ csr_src,
    const float* __restrict__ dinv, const float* __restrict__ zs,
    const float* __restrict__ b2, float* __restrict__ out, int N) {
  int wave = (blockIdx.x * blockDim.x + threadIdx.x) >> 6;
  int lane = threadIdx.x & 63;
  int sub = lane >> 4;   // 0..3
  int l = lane & 15;
  int d = wave * 4 + sub;
  bool valid = d < N;
  if (!valid) d = N - 1;
  float dd = dinv[d];
  int beg = rowptr[d], end = rowptr[d + 1];

  float acc = 0.f;
  for (int e = beg + l; e < end; e += 16) {
    acc += zs[csr_src[e]];
  }
#pragma unroll
  for (int off = 8; off > 0; off >>= 1) acc += __shfl_down(acc, off, 16);
  if (l == 0 && valid) out[d] = b2[0] + dd * (zs[d] + acc);
}

// ---------------------------------------------------------------------------
extern "C" void kernel_launch(void* const* d_in, const int* in_sizes, int n_in,
                              void* d_out, int out_size, void* d_ws, size_t ws_size,
                              hipStream_t stream) {
  const float* x  = (const float*)d_in[0];
  const int*   ei = (const int*)d_in[1];   // [2,E] int32
  const float* W1 = (const float*)d_in[2];
  const float* b1 = (const float*)d_in[3];
  const float* W2 = (const float*)d_in[4];
  const float* b2 = (const float*)d_in[5];
  float* out = (float*)d_out;

  const int E = in_sizes[1] / 2;
  const int N = in_sizes[0] / 512;  // 50000
  const int* src = ei;
  const int* dst = ei + E;

  char* ws = (char*)d_ws;
  size_t off = 0;
  auto alloc = [&](size_t bytes) -> void* {
    void* p = ws + off;
    off += (bytes + 255) & ~(size_t)255;
    return p;
  };
  int*   deg     = (int*)  alloc((size_t)N * 4);
  int*   rowptr  = (int*)  alloc((size_t)(N + 1) * 4);
  int*   cursor  = (int*)  alloc((size_t)N * 4);
  int*   csr_src = (int*)  alloc((size_t)E * 4);          // 3.2 MB
  int*   sums    = (int*)  alloc(1024 * 4);
  float* dinv    = (float*)alloc((size_t)N * 4);
  f16*   hs      = (f16*)  alloc((size_t)N * 256 * 2);    // 25.6 MB
  float* zs      = (float*)alloc((size_t)N * 4);
  f16*   Bpk     = (f16*)  alloc(512 * 256 * 2);          // 256 KB packed W1

  const int nb = (N + 255) / 256;  // scan blocks

  hipMemsetAsync(deg, 0, (size_t)N * 4, stream);
  k_prep_w1t<<<(512 * 256 + 255) / 256, 256, 0, stream>>>(W1, Bpk);
  k_deg<<<(E + 255) / 256, 256, 0, stream>>>(dst, E, deg);
  k_scan1<<<nb, 256, 0, stream>>>(deg, rowptr, sums, dinv, N);
  k_scan2<<<1, 1024, 0, stream>>>(sums, nb);
  k_scan3<<<(N + 255) / 256, 256, 0, stream>>>(rowptr, cursor, sums, N, E);
  k_bucket<<<(E + 255) / 256, 256, 0, stream>>>(src, dst, cursor, csr_src, E);

  k_gemm_mfma<<<(N + 63) / 64, 256, 0, stream>>>(x, (const uint4*)Bpk, dinv, hs, N);

  const int nwaves1 = (N + 1) / 2;  // 2 nodes per wave
  k_gather_fused<<<(nwaves1 * 64 + 255) / 256, 256, 0, stream>>>(rowptr, csr_src, dinv, hs,
                                                                 b1, W2, zs, N);
  const int nwaves2 = (N + 3) / 4;  // 4 nodes per wave
  k_gather2<<<(nwaves2 * 64 + 255) / 256, 256, 0, stream>>>(rowptr, csr_src, dinv, zs, b2, out, N);
}